// Round 10
// baseline (490.040 us; speedup 1.0000x reference)
//
#include <hip/hip_runtime.h>
#include <hip/hip_bf16.h>

#define F_IN 512
#define H1 8
#define D1 8
#define F_MID 64   // H1*D1
#define C 16
#define NEG_SLOPE 0.2f
#define BIN_CHUNK 16384       // big chunks -> long per-bucket runs -> minimal cross-XCD line sharing
#define NB_MAX 1024
#define BUCKET_SHIFT 7        // 128 nodes per bucket
#define BUCKET_STRIDE 3072    // capacity per bucket (mean 2048, +22 sigma)
#define SRC_BITS 17           // n_nodes = 100000 < 2^17
#define SRC_MASK ((1 << SRC_BITS) - 1)

typedef __attribute__((ext_vector_type(8))) short bf16x8;
typedef __attribute__((ext_vector_type(4))) float f32x4;

static __device__ __forceinline__ unsigned short f2bf(float f) {
    __hip_bfloat16 h = __float2bfloat16(f);
    return *(unsigned short*)&h;
}

// ============ prologue: W1 transpose (blocks 0..127) + gcur zero (block 128) ============
__global__ __launch_bounds__(256) void k_init(const float* __restrict__ W1,
                                              __hip_bfloat16* __restrict__ w1t,
                                              int* __restrict__ gcur) {
    const int t = threadIdx.x;
    if ((int)blockIdx.x == (F_IN * F_MID) / 256) {
        for (int i = t; i < NB_MAX; i += 256) gcur[i] = 0;
        return;
    }
    int idx = blockIdx.x * 256 + t;
    int k = idx >> 6, n = idx & 63;
    w1t[n * F_IN + k] = __float2bfloat16(W1[idx]);
}

// ============ fused heterogeneous: bucket-bin (blocks < nbin) + Layer-1 GEMM (rest) ============
// bin: 16K-edge chunks; dst read twice (L2-resident) instead of register-cached.
__global__ __launch_bounds__(256) void k_bin_gemm1(const int* __restrict__ src,
                                                   const int* __restrict__ dst,
                                                   int* __restrict__ gcur,
                                                   int* __restrict__ bucketed,
                                                   const float* __restrict__ x,
                                                   const __hip_bfloat16* __restrict__ w1t,
                                                   const float* __restrict__ a1s,
                                                   const float* __restrict__ a1d,
                                                   __hip_bfloat16* __restrict__ h1b,
                                                   float* __restrict__ es1,
                                                   float* __restrict__ ed1,
                                                   int n_edges, int nb, int nbin, int n_nodes) {
    __shared__ int cnt[NB_MAX];
    __shared__ int base[NB_MAX];
    const int t = threadIdx.x;

    if ((int)blockIdx.x < nbin) {
        // ---------------- bin path ----------------
        const int eb = blockIdx.x * BIN_CHUNK;
        const int ecnt = min(BIN_CHUNK, n_edges - eb);
        for (int b = t; b < nb; b += 256) cnt[b] = 0;
        __syncthreads();
        // pass 1: histogram (dst from L2/L3)
        for (int i = t; i < ecnt; i += 256)
            atomicAdd(&cnt[dst[eb + i] >> BUCKET_SHIFT], 1);
        __syncthreads();
        for (int b = t; b < nb; b += 256) {
            int c = cnt[b];
            base[b] = c > 0 ? atomicAdd(&gcur[b], c) : 0;
            cnt[b] = 0;
        }
        __syncthreads();
        // pass 2: placement (dst re-read, L2-hit)
        for (int i = t; i < ecnt; i += 256) {
            int e = eb + i;
            int d = dst[e];
            int b = d >> BUCKET_SHIFT;
            int local = atomicAdd(&cnt[b], 1);
            bucketed[(size_t)b * BUCKET_STRIDE + base[b] + local] =
                ((d & ((1 << BUCKET_SHIFT) - 1)) << SRC_BITS) | src[e];
        }
        return;
    }

    // ---------------- gemm1 path (zero LDS use, zero barriers) ----------------
    const int wv = t >> 6, l = t & 63;
    const int q = l >> 4, m16 = l & 15;
    const int rowbase = ((int)blockIdx.x - nbin) * 64;

    const int node = rowbase + wv * 16 + m16;
    const int gx = node < n_nodes ? node : n_nodes - 1;
    const float* xrow = x + (size_t)gx * F_IN;

    f32x4 acc[4];
#pragma unroll
    for (int i = 0; i < 4; ++i) acc[i] = (f32x4){0.f, 0.f, 0.f, 0.f};

    for (int kt = 0; kt < F_IN; kt += 64) {
#pragma unroll
        for (int kk = 0; kk < 2; ++kk) {
            const float* xp = xrow + kt + kk * 32 + q * 8;
            float4 v0 = *(const float4*)(xp);
            float4 v1 = *(const float4*)(xp + 4);
            ushort4 b0, b1;
            b0.x = f2bf(v0.x); b0.y = f2bf(v0.y); b0.z = f2bf(v0.z); b0.w = f2bf(v0.w);
            b1.x = f2bf(v1.x); b1.y = f2bf(v1.y); b1.z = f2bf(v1.z); b1.w = f2bf(v1.w);
            union { ushort4 u4[2]; bf16x8 v8; } bu;
            bu.u4[0] = b0; bu.u4[1] = b1;
            const bf16x8 bfrag = bu.v8;
#pragma unroll
            for (int tn = 0; tn < 4; ++tn) {
                bf16x8 afrag = *(const bf16x8*)(w1t + (size_t)(tn * 16 + m16) * F_IN
                                                + kt + kk * 32 + q * 8);
                acc[tn] = __builtin_amdgcn_mfma_f32_16x16x32_bf16(afrag, bfrag, acc[tn], 0, 0, 0);
            }
        }
    }

    const bool ok = node < n_nodes;
#pragma unroll
    for (int tn = 0; tn < 4; ++tn) {
        const f32x4 a = acc[tn];
        const int nw0 = tn * 16 + q * 4;
        float vs = a.x * a1s[nw0] + a.y * a1s[nw0 + 1] + a.z * a1s[nw0 + 2] + a.w * a1s[nw0 + 3];
        float vd = a.x * a1d[nw0] + a.y * a1d[nw0 + 1] + a.z * a1d[nw0 + 2] + a.w * a1d[nw0 + 3];
        vs += __shfl_xor(vs, 16, 64);
        vd += __shfl_xor(vd, 16, 64);
        if (ok) {
            ushort4 b;
            b.x = f2bf(a.x); b.y = f2bf(a.y); b.z = f2bf(a.z); b.w = f2bf(a.w);
            *(ushort4*)(h1b + (size_t)node * F_MID + nw0) = b;
            if ((q & 1) == 0) {
                const int head = 2 * tn + (q >> 1);
                es1[node * H1 + head] = vs;
                ed1[node * H1 + head] = vd;
            }
        }
    }
}

// ============ fused per-bucket: prefix + histogram + local scan + LDS-staged placement ============
// sorted output built in LDS, flushed contiguously -> no scattered 4B global writes
__global__ __launch_bounds__(256) void k_place(const int* __restrict__ gcur,
                                               const int* __restrict__ bucketed,
                                               int* __restrict__ row_start,
                                               int* __restrict__ sorted_src,
                                               int n_nodes, int n_edges) {
    __shared__ int stage[BUCKET_STRIDE];
    __shared__ int sstage[BUCKET_STRIDE];
    __shared__ int cnt[1 << BUCKET_SHIFT];
    __shared__ int cur[1 << BUCKET_SHIFT];
    __shared__ int wsum[4];
    const int t = threadIdx.x;
    const int b = blockIdx.x;
    if (t < (1 << BUCKET_SHIFT)) cnt[t] = 0;
    // exclusive prefix over bucket totals: base0 = sum(gcur[0..b-1]) (L2-resident)
    int pre = 0;
    for (int j = t; j < b; j += 256) pre += gcur[j];
#pragma unroll
    for (int off = 1; off < 64; off <<= 1) pre += __shfl_xor(pre, off, 64);
    if ((t & 63) == 0) wsum[t >> 6] = pre;
    __syncthreads();
    const int base0 = wsum[0] + wsum[1] + wsum[2] + wsum[3];
    if (b == 0 && t == 0) row_start[n_nodes] = n_edges;

    const int total = gcur[b];
    const int* bp = bucketed + (size_t)b * BUCKET_STRIDE;
    for (int i = t; i < total; i += 256) {
        int e = bp[i];
        stage[i] = e;
        atomicAdd(&cnt[e >> SRC_BITS], 1);
    }
    __syncthreads();
    // inclusive Hillis-Steele over 128 counts
    if (t < (1 << BUCKET_SHIFT)) cur[t] = cnt[t];
    __syncthreads();
#pragma unroll
    for (int d = 1; d < (1 << BUCKET_SHIFT); d <<= 1) {
        int u = 0;
        if (t < (1 << BUCKET_SHIFT) && t >= d) u = cur[t - d];
        __syncthreads();
        if (t < (1 << BUCKET_SHIFT)) cur[t] += u;
        __syncthreads();
    }
    if (t < (1 << BUCKET_SHIFT)) {
        int node = (b << BUCKET_SHIFT) + t;
        int excl = cur[t] - cnt[t];
        if (node < n_nodes) row_start[node] = base0 + excl;
        cur[t] = excl;   // becomes the per-node cursor
    }
    __syncthreads();
    // placement into LDS (scatter stays on-chip)
    for (int i = t; i < total; i += 256) {
        int e = stage[i];
        int p = atomicAdd(&cur[e >> SRC_BITS], 1);
        sstage[p] = e & SRC_MASK;
    }
    __syncthreads();
    // contiguous coalesced flush (full-line global writes)
    for (int i = t; i < total; i += 256)
        sorted_src[base0 + i] = sstage[i];
}

// ============ Layer 1 gather: wave per node, lane = feature, 8-wide edge unroll ============
__global__ __launch_bounds__(256) void k_gather1(const int* __restrict__ row_start,
                                                 const int* __restrict__ sorted_src,
                                                 const __hip_bfloat16* __restrict__ h1b,
                                                 const float* __restrict__ es1,
                                                 const float* __restrict__ ed1,
                                                 __hip_bfloat16* __restrict__ h1c, int n_nodes) {
    const int n = blockIdx.x * 4 + (threadIdx.x >> 6);
    if (n >= n_nodes) return;
    const int lane = threadIdx.x & 63;
    const int h = lane >> 3;
    const float edh = ed1[n * H1 + h];
    const int beg = row_start[n], end = row_start[n + 1];
    float acc = 0.f, den = 0.f;
    for (int base = beg; base < end; base += 64) {
        const int m = min(64, end - base);
        const int li = lane < m ? lane : (m - 1);
        const int myS = sorted_src[base + li];
        int j = 0;
        for (; j + 8 <= m; j += 8) {
            const int s0 = __shfl(myS, j, 64),     s1 = __shfl(myS, j + 1, 64);
            const int s2 = __shfl(myS, j + 2, 64), s3 = __shfl(myS, j + 3, 64);
            const int s4 = __shfl(myS, j + 4, 64), s5 = __shfl(myS, j + 5, 64);
            const int s6 = __shfl(myS, j + 6, 64), s7 = __shfl(myS, j + 7, 64);
            float e0 = es1[s0 * H1 + h], e1 = es1[s1 * H1 + h];
            float e2 = es1[s2 * H1 + h], e3 = es1[s3 * H1 + h];
            float e4 = es1[s4 * H1 + h], e5 = es1[s5 * H1 + h];
            float e6 = es1[s6 * H1 + h], e7 = es1[s7 * H1 + h];
            const float f0 = __bfloat162float(h1b[(size_t)s0 * F_MID + lane]);
            const float f1 = __bfloat162float(h1b[(size_t)s1 * F_MID + lane]);
            const float f2 = __bfloat162float(h1b[(size_t)s2 * F_MID + lane]);
            const float f3 = __bfloat162float(h1b[(size_t)s3 * F_MID + lane]);
            const float f4 = __bfloat162float(h1b[(size_t)s4 * F_MID + lane]);
            const float f5 = __bfloat162float(h1b[(size_t)s5 * F_MID + lane]);
            const float f6 = __bfloat162float(h1b[(size_t)s6 * F_MID + lane]);
            const float f7 = __bfloat162float(h1b[(size_t)s7 * F_MID + lane]);
            e0 += edh; e1 += edh; e2 += edh; e3 += edh;
            e4 += edh; e5 += edh; e6 += edh; e7 += edh;
            e0 = e0 > 0.f ? e0 : NEG_SLOPE * e0;
            e1 = e1 > 0.f ? e1 : NEG_SLOPE * e1;
            e2 = e2 > 0.f ? e2 : NEG_SLOPE * e2;
            e3 = e3 > 0.f ? e3 : NEG_SLOPE * e3;
            e4 = e4 > 0.f ? e4 : NEG_SLOPE * e4;
            e5 = e5 > 0.f ? e5 : NEG_SLOPE * e5;
            e6 = e6 > 0.f ? e6 : NEG_SLOPE * e6;
            e7 = e7 > 0.f ? e7 : NEG_SLOPE * e7;
            const float w0 = __expf(e0), w1 = __expf(e1), w2 = __expf(e2), w3 = __expf(e3);
            const float w4 = __expf(e4), w5 = __expf(e5), w6 = __expf(e6), w7 = __expf(e7);
            acc += (w0 * f0 + w1 * f1 + w2 * f2 + w3 * f3)
                 + (w4 * f4 + w5 * f5 + w6 * f6 + w7 * f7);
            den += ((w0 + w1) + (w2 + w3)) + ((w4 + w5) + (w6 + w7));
        }
        for (; j + 4 <= m; j += 4) {
            const int s0 = __shfl(myS, j, 64), s1 = __shfl(myS, j + 1, 64);
            const int s2 = __shfl(myS, j + 2, 64), s3 = __shfl(myS, j + 3, 64);
            float e0 = es1[s0 * H1 + h], e1 = es1[s1 * H1 + h];
            float e2 = es1[s2 * H1 + h], e3 = es1[s3 * H1 + h];
            const float f0 = __bfloat162float(h1b[(size_t)s0 * F_MID + lane]);
            const float f1 = __bfloat162float(h1b[(size_t)s1 * F_MID + lane]);
            const float f2 = __bfloat162float(h1b[(size_t)s2 * F_MID + lane]);
            const float f3 = __bfloat162float(h1b[(size_t)s3 * F_MID + lane]);
            e0 += edh; e1 += edh; e2 += edh; e3 += edh;
            e0 = e0 > 0.f ? e0 : NEG_SLOPE * e0;
            e1 = e1 > 0.f ? e1 : NEG_SLOPE * e1;
            e2 = e2 > 0.f ? e2 : NEG_SLOPE * e2;
            e3 = e3 > 0.f ? e3 : NEG_SLOPE * e3;
            const float w0 = __expf(e0), w1 = __expf(e1), w2 = __expf(e2), w3 = __expf(e3);
            acc += w0 * f0 + w1 * f1 + w2 * f2 + w3 * f3;
            den += (w0 + w1) + (w2 + w3);
        }
        for (; j < m; ++j) {
            const int s = __shfl(myS, j, 64);
            float ev = es1[s * H1 + h] + edh;
            ev = ev > 0.f ? ev : NEG_SLOPE * ev;
            const float w = __expf(ev);
            acc += w * __bfloat162float(h1b[(size_t)s * F_MID + lane]);
            den += w;
        }
    }
    float evs = es1[n * H1 + h] + edh;
    evs = evs > 0.f ? evs : NEG_SLOPE * evs;
    const float ws = __expf(evs);
    acc += ws * __bfloat162float(h1b[(size_t)n * F_MID + lane]);
    den += ws;
    float v = acc / den;
    v = v > 0.f ? v : expm1f(v);   // ELU
    h1c[(size_t)n * F_MID + lane] = __float2bfloat16(v);
}

// ============ Layer 2 transform: h1c[N,64] bf16 @ W2[64,16] -> h2b (bf16) + es2/ed2 ============
__global__ void k_gemm2(const __hip_bfloat16* __restrict__ h1c, const float* __restrict__ W2,
                        const float* __restrict__ a2s, const float* __restrict__ a2d,
                        __hip_bfloat16* __restrict__ h2b, float* __restrict__ es2,
                        float* __restrict__ ed2, int n_nodes) {
    __shared__ float w2s[F_MID * C];
    __shared__ float h1s[16][F_MID + 1];
    const int t = threadIdx.x;
    const int nb = blockIdx.x * 16;
    for (int i = t; i < F_MID * C; i += 256) w2s[i] = W2[i];
    {
        // 16 rows x 16 ushort4-groups = 256 units, one per thread
        int r = t >> 4, k4 = (t & 15) << 2;
        int n = nb + r;
        const __hip_bfloat16* p = h1c + (size_t)(n < n_nodes ? n : n_nodes - 1) * F_MID + k4;
        ushort4 v = *(const ushort4*)p;
        h1s[r][k4 + 0] = __bfloat162float(*(const __hip_bfloat16*)&v.x);
        h1s[r][k4 + 1] = __bfloat162float(*(const __hip_bfloat16*)&v.y);
        h1s[r][k4 + 2] = __bfloat162float(*(const __hip_bfloat16*)&v.z);
        h1s[r][k4 + 3] = __bfloat162float(*(const __hip_bfloat16*)&v.w);
    }
    __syncthreads();
    const int r = t >> 4, c = t & 15;
    const int n = nb + r;
    float acc = 0.f;
#pragma unroll
    for (int k = 0; k < F_MID; ++k) acc += h1s[r][k] * w2s[k * C + c];
    float vs = acc * a2s[c], vd = acc * a2d[c];
#pragma unroll
    for (int off = 1; off < 16; off <<= 1) {
        vs += __shfl_xor(vs, off, 64);
        vd += __shfl_xor(vd, off, 64);
    }
    if (n < n_nodes) {
        h2b[(size_t)n * C + c] = __float2bfloat16(acc);
        if (c == 0) { es2[n] = vs; ed2[n] = vd; }
    }
}

// ============ Layer 2 gather + log_softmax: weights precomputed per-lane (parallel es2 loads) ============
__global__ __launch_bounds__(256) void k_gather2(const int* __restrict__ row_start,
                                                 const int* __restrict__ sorted_src,
                                                 const __hip_bfloat16* __restrict__ h2b,
                                                 const float* __restrict__ es2,
                                                 const float* __restrict__ ed2,
                                                 float* __restrict__ out, int n_nodes) {
    const int n = blockIdx.x * 16 + (threadIdx.x >> 4);
    if (n >= n_nodes) return;
    const int lane = threadIdx.x & 63;
    const int c = lane & 15;
    const int g = lane >> 4;
    const float ed = ed2[n];
    const int beg = row_start[n], end = row_start[n + 1];
    float acc = 0.f, den = 0.f;
    for (int base = beg; base < end; base += 16) {
        const int m = min(16, end - base);
        const int li = c < m ? c : (m - 1);
        const int myS = sorted_src[base + li];
        // parallel weight precompute: one es2 load per lane, all in flight at once
        float evp = es2[myS] + ed;
        evp = evp > 0.f ? evp : NEG_SLOPE * evp;
        const float wli = __expf(evp);
        int j = 0;
        for (; j + 4 <= m; j += 4) {
            const int s0 = __shfl(myS, g * 16 + j, 64), s1 = __shfl(myS, g * 16 + j + 1, 64);
            const int s2 = __shfl(myS, g * 16 + j + 2, 64), s3 = __shfl(myS, g * 16 + j + 3, 64);
            const float w0 = __shfl(wli, g * 16 + j, 64), w1 = __shfl(wli, g * 16 + j + 1, 64);
            const float w2 = __shfl(wli, g * 16 + j + 2, 64), w3 = __shfl(wli, g * 16 + j + 3, 64);
            const float f0 = __bfloat162float(h2b[(size_t)s0 * C + c]);
            const float f1 = __bfloat162float(h2b[(size_t)s1 * C + c]);
            const float f2 = __bfloat162float(h2b[(size_t)s2 * C + c]);
            const float f3 = __bfloat162float(h2b[(size_t)s3 * C + c]);
            acc += w0 * f0 + w1 * f1 + w2 * f2 + w3 * f3;
            den += (w0 + w1) + (w2 + w3);
        }
        for (; j < m; ++j) {
            const int s = __shfl(myS, g * 16 + j, 64);
            const float w = __shfl(wli, g * 16 + j, 64);
            acc += w * __bfloat162float(h2b[(size_t)s * C + c]);
            den += w;
        }
    }
    float evs = es2[n] + ed;
    evs = evs > 0.f ? evs : NEG_SLOPE * evs;
    const float ws = __expf(evs);
    acc += ws * __bfloat162float(h2b[(size_t)n * C + c]);
    den += ws;
    const float v = acc / den;
    float mx = v;
#pragma unroll
    for (int off = 1; off < 16; off <<= 1) mx = fmaxf(mx, __shfl_xor(mx, off, 64));
    float se = __expf(v - mx);
#pragma unroll
    for (int off = 1; off < 16; off <<= 1) se += __shfl_xor(se, off, 64);
    out[(size_t)n * C + c] = v - mx - __logf(se);
}

extern "C" void kernel_launch(void* const* d_in, const int* in_sizes, int n_in,
                              void* d_out, int out_size, void* d_ws, size_t ws_size,
                              hipStream_t stream) {
    const float* x   = (const float*)d_in[0];
    const int*   ei  = (const int*)d_in[1];
    const float* W1  = (const float*)d_in[2];
    const float* a1s = (const float*)d_in[3];
    const float* a1d = (const float*)d_in[4];
    const float* W2  = (const float*)d_in[5];
    const float* a2s = (const float*)d_in[6];
    const float* a2d = (const float*)d_in[7];
    float* out = (float*)d_out;

    const int n_nodes = in_sizes[0] / F_IN;   // 100000
    const int n_edges = in_sizes[1] / 2;      // 1600000
    const int* src = ei;
    const int* dst = ei + n_edges;
    const int nb = (n_nodes + (1 << BUCKET_SHIFT) - 1) >> BUCKET_SHIFT;   // 782
    const int nbin = (n_edges + BIN_CHUNK - 1) / BIN_CHUNK;               // 98
    const int ngemm = (n_nodes + 63) / 64;                                // 1563

    // workspace layout
    float* fws = (float*)d_ws;
    float* es1 = fws;                              // N*8
    float* ed1 = es1 + (size_t)n_nodes * H1;       // N*8
    float* es2 = ed1 + (size_t)n_nodes * H1;       // N
    float* ed2 = es2 + n_nodes;                    // N
    __hip_bfloat16* h1b = (__hip_bfloat16*)(ed2 + n_nodes);   // N*64 bf16
    __hip_bfloat16* h2b = h1b + (size_t)n_nodes * F_MID;      // N*16 bf16
    __hip_bfloat16* h1c = h2b + (size_t)n_nodes * C;          // N*64 bf16 (post-ELU)
    __hip_bfloat16* w1t = h1c + (size_t)n_nodes * F_MID;      // 64*512 bf16
    int* iws         = (int*)(w1t + F_IN * F_MID);
    int* gcur        = iws;                        // NB_MAX (zeroed by k_init)
    int* row_start   = gcur + NB_MAX;              // N+1
    int* sorted_src  = row_start + n_nodes + 1;    // E
    int* bucketed    = sorted_src + n_edges;       // NB_MAX*3072 int (packed)

    // prologue: w1t transpose + gcur zero
    k_init<<<(F_IN * F_MID) / 256 + 1, 256, 0, stream>>>(W1, w1t, gcur);

    // CSR bin + Layer-1 GEMM (fused heterogeneous grid; mutually independent)
    k_bin_gemm1<<<nbin + ngemm, 256, 0, stream>>>(src, dst, gcur, bucketed,
                                                  x, w1t, a1s, a1d, h1b, es1, ed1,
                                                  n_edges, nb, nbin, n_nodes);

    // CSR place (LDS-staged coalesced output)
    k_place<<<nb, 256, 0, stream>>>(gcur, bucketed, row_start, sorted_src, n_nodes, n_edges);

    // Layer 1 gather
    k_gather1<<<(n_nodes + 3) / 4, 256, 0, stream>>>(row_start, sorted_src, h1b, es1, ed1, h1c, n_nodes);

    // Layer 2
    k_gemm2<<<(n_nodes + 15) / 16, 256, 0, stream>>>(h1c, W2, a2s, a2d, h2b, es2, ed2, n_nodes);
    k_gather2<<<(n_nodes + 15) / 16, 256, 0, stream>>>(row_start, sorted_src, h2b, es2, ed2, out, n_nodes);
}

// Round 11
// 478.235 us; speedup vs baseline: 1.0247x; 1.0247x over previous
//
#include <hip/hip_runtime.h>
#include <hip/hip_bf16.h>

#define F_IN 512
#define H1 8
#define D1 8
#define F_MID 64   // H1*D1
#define C 16
#define NEG_SLOPE 0.2f
#define BIN_CHUNK 4096
#define NB_MAX 1024
#define BUCKET_SHIFT 7        // 128 nodes per bucket
#define BUCKET_STRIDE 3072    // capacity per bucket (mean 2048, +22 sigma)
#define SRC_BITS 17           // n_nodes = 100000 < 2^17
#define SRC_MASK ((1 << SRC_BITS) - 1)

typedef __attribute__((ext_vector_type(8))) short bf16x8;
typedef __attribute__((ext_vector_type(4))) float f32x4;

static __device__ __forceinline__ unsigned short f2bf(float f) {
    __hip_bfloat16 h = __float2bfloat16(f);
    return *(unsigned short*)&h;
}

// ============ prologue: W1 transpose (blocks 0..127) + gcur zero (block 128) ============
__global__ __launch_bounds__(256) void k_init(const float* __restrict__ W1,
                                              __hip_bfloat16* __restrict__ w1t,
                                              int* __restrict__ gcur) {
    const int t = threadIdx.x;
    if ((int)blockIdx.x == (F_IN * F_MID) / 256) {
        for (int i = t; i < NB_MAX; i += 256) gcur[i] = 0;
        return;
    }
    int idx = blockIdx.x * 256 + t;
    int k = idx >> 6, n = idx & 63;
    w1t[n * F_IN + k] = __float2bfloat16(W1[idx]);
}

// ============ bucket-bin with block-local counting sort (coalesced bucketed writes) ============
// histogram -> LDS exclusive scan -> bucket-sorted LDS stage -> run-coalesced flush.
// Replaces 64-lane scattered 4B stores with ~12 run-coalesced transactions per wave.
__global__ __launch_bounds__(256) void k_bin(const int* __restrict__ src,
                                             const int* __restrict__ dst,
                                             int* __restrict__ gcur,
                                             int* __restrict__ bucketed,
                                             int n_edges) {
    __shared__ int cnt[NB_MAX];
    __shared__ int excl[NB_MAX];
    __shared__ int gbase[NB_MAX];
    __shared__ int curloc[NB_MAX];
    __shared__ int stage[BIN_CHUNK];
    __shared__ unsigned short sbkt[BIN_CHUNK];
    __shared__ int wtot[4];
    const int t = threadIdx.x;
    const int lane = t & 63, w = t >> 6;
    const int eb = blockIdx.x * BIN_CHUNK;
    const int ecnt = min(BIN_CHUNK, n_edges - eb);

    // cache dst chunk in registers (single HBM read of dst)
    int dc[BIN_CHUNK / 256];
#pragma unroll
    for (int i = 0; i < BIN_CHUNK / 256; ++i) {
        int e = eb + i * 256 + t;
        dc[i] = (e < n_edges) ? dst[e] : -1;
    }
    for (int b = t; b < NB_MAX; b += 256) cnt[b] = 0;
    __syncthreads();
#pragma unroll
    for (int i = 0; i < BIN_CHUNK / 256; ++i)
        if (dc[i] >= 0) atomicAdd(&cnt[dc[i] >> BUCKET_SHIFT], 1);
    __syncthreads();

    // exclusive scan over cnt[0..1023]: 4 entries/thread + wave scan + wave-total combine
    const int c0 = cnt[4 * t], c1 = cnt[4 * t + 1], c2 = cnt[4 * t + 2], c3 = cnt[4 * t + 3];
    const int ls = c0 + c1 + c2 + c3;
    int is = ls;
#pragma unroll
    for (int off = 1; off < 64; off <<= 1) {
        int v = __shfl_up(is, off, 64);
        if (lane >= off) is += v;
    }
    if (lane == 63) wtot[w] = is;
    __syncthreads();
    int woff = 0;
#pragma unroll
    for (int i = 0; i < 4; ++i) if (i < w) woff += wtot[i];
    const int e0 = woff + is - ls;   // exclusive prefix at bucket 4t
    excl[4 * t] = e0;               curloc[4 * t] = e0;
    excl[4 * t + 1] = e0 + c0;      curloc[4 * t + 1] = e0 + c0;
    excl[4 * t + 2] = e0 + c0 + c1; curloc[4 * t + 2] = e0 + c0 + c1;
    excl[4 * t + 3] = e0 + c0 + c1 + c2; curloc[4 * t + 3] = e0 + c0 + c1 + c2;
    // global reservation (one atomic per non-empty bucket)
    gbase[4 * t]     = c0 > 0 ? atomicAdd(&gcur[4 * t], c0) : 0;
    gbase[4 * t + 1] = c1 > 0 ? atomicAdd(&gcur[4 * t + 1], c1) : 0;
    gbase[4 * t + 2] = c2 > 0 ? atomicAdd(&gcur[4 * t + 2], c2) : 0;
    gbase[4 * t + 3] = c3 > 0 ? atomicAdd(&gcur[4 * t + 3], c3) : 0;
    __syncthreads();

    // pass 2: place packed edges into bucket-sorted LDS stage
#pragma unroll
    for (int i = 0; i < BIN_CHUNK / 256; ++i) {
        if (dc[i] >= 0) {
            int e = eb + i * 256 + t;
            int d = dc[i];
            int b = d >> BUCKET_SHIFT;
            int p = atomicAdd(&curloc[b], 1);
            stage[p] = ((d & ((1 << BUCKET_SHIFT) - 1)) << SRC_BITS) | src[e];
            sbkt[p] = (unsigned short)b;
        }
    }
    __syncthreads();
    // run-coalesced flush: consecutive i -> consecutive global slots within each bucket run
    for (int i = t; i < ecnt; i += 256) {
        int b = sbkt[i];
        bucketed[(size_t)b * BUCKET_STRIDE + gbase[b] + (i - excl[b])] = stage[i];
    }
}

// ============ fused heterogeneous launch: gemm1 (blocks < ngemm) + place (blocks >= ngemm) ====
__global__ __launch_bounds__(256) void k_gemm1_place(const float* __restrict__ x,
                                                     const __hip_bfloat16* __restrict__ w1t,
                                                     const float* __restrict__ a1s,
                                                     const float* __restrict__ a1d,
                                                     __hip_bfloat16* __restrict__ h1b,
                                                     float* __restrict__ es1,
                                                     float* __restrict__ ed1,
                                                     const int* __restrict__ gcur,
                                                     const int* __restrict__ bucketed,
                                                     int* __restrict__ row_start,
                                                     int* __restrict__ sorted_src,
                                                     int n_nodes, int n_edges, int ngemm) {
    __shared__ int stage[BUCKET_STRIDE];
    __shared__ int sstage[BUCKET_STRIDE];
    __shared__ int cnt[1 << BUCKET_SHIFT];
    __shared__ int cur[1 << BUCKET_SHIFT];
    __shared__ int wsum[4];
    const int t = threadIdx.x;

    if ((int)blockIdx.x < ngemm) {
        // ---------------- gemm1 path (zero LDS use, zero barriers) ----------------
        const int wv = t >> 6, l = t & 63;
        const int q = l >> 4, m16 = l & 15;
        const int rowbase = blockIdx.x * 64;

        const int node = rowbase + wv * 16 + m16;
        const int gx = node < n_nodes ? node : n_nodes - 1;
        const float* xrow = x + (size_t)gx * F_IN;

        f32x4 acc[4];
#pragma unroll
        for (int i = 0; i < 4; ++i) acc[i] = (f32x4){0.f, 0.f, 0.f, 0.f};

        for (int kt = 0; kt < F_IN; kt += 64) {
#pragma unroll
            for (int kk = 0; kk < 2; ++kk) {
                const float* xp = xrow + kt + kk * 32 + q * 8;
                float4 v0 = *(const float4*)(xp);
                float4 v1 = *(const float4*)(xp + 4);
                ushort4 b0, b1;
                b0.x = f2bf(v0.x); b0.y = f2bf(v0.y); b0.z = f2bf(v0.z); b0.w = f2bf(v0.w);
                b1.x = f2bf(v1.x); b1.y = f2bf(v1.y); b1.z = f2bf(v1.z); b1.w = f2bf(v1.w);
                union { ushort4 u4[2]; bf16x8 v8; } bu;
                bu.u4[0] = b0; bu.u4[1] = b1;
                const bf16x8 bfrag = bu.v8;
#pragma unroll
                for (int tn = 0; tn < 4; ++tn) {
                    bf16x8 afrag = *(const bf16x8*)(w1t + (size_t)(tn * 16 + m16) * F_IN
                                                    + kt + kk * 32 + q * 8);
                    acc[tn] = __builtin_amdgcn_mfma_f32_16x16x32_bf16(afrag, bfrag, acc[tn], 0, 0, 0);
                }
            }
        }

        const bool ok = node < n_nodes;
#pragma unroll
        for (int tn = 0; tn < 4; ++tn) {
            const f32x4 a = acc[tn];
            const int nw0 = tn * 16 + q * 4;
            float vs = a.x * a1s[nw0] + a.y * a1s[nw0 + 1] + a.z * a1s[nw0 + 2] + a.w * a1s[nw0 + 3];
            float vd = a.x * a1d[nw0] + a.y * a1d[nw0 + 1] + a.z * a1d[nw0 + 2] + a.w * a1d[nw0 + 3];
            vs += __shfl_xor(vs, 16, 64);
            vd += __shfl_xor(vd, 16, 64);
            if (ok) {
                ushort4 b;
                b.x = f2bf(a.x); b.y = f2bf(a.y); b.z = f2bf(a.z); b.w = f2bf(a.w);
                *(ushort4*)(h1b + (size_t)node * F_MID + nw0) = b;
                if ((q & 1) == 0) {
                    const int head = 2 * tn + (q >> 1);
                    es1[node * H1 + head] = vs;
                    ed1[node * H1 + head] = vd;
                }
            }
        }
        return;
    }

    // ---------------- place path (LDS-staged coalesced output) ----------------
    const int b = (int)blockIdx.x - ngemm;
    if (t < (1 << BUCKET_SHIFT)) cnt[t] = 0;
    int pre = 0;
    for (int j = t; j < b; j += 256) pre += gcur[j];
#pragma unroll
    for (int off = 1; off < 64; off <<= 1) pre += __shfl_xor(pre, off, 64);
    if ((t & 63) == 0) wsum[t >> 6] = pre;
    __syncthreads();
    const int base0 = wsum[0] + wsum[1] + wsum[2] + wsum[3];
    if (b == 0 && t == 0) row_start[n_nodes] = n_edges;

    const int total = gcur[b];
    const int* bp = bucketed + (size_t)b * BUCKET_STRIDE;
    for (int i = t; i < total; i += 256) {
        int e = bp[i];
        stage[i] = e;
        atomicAdd(&cnt[e >> SRC_BITS], 1);
    }
    __syncthreads();
    if (t < (1 << BUCKET_SHIFT)) cur[t] = cnt[t];
    __syncthreads();
#pragma unroll
    for (int d = 1; d < (1 << BUCKET_SHIFT); d <<= 1) {
        int u = 0;
        if (t < (1 << BUCKET_SHIFT) && t >= d) u = cur[t - d];
        __syncthreads();
        if (t < (1 << BUCKET_SHIFT)) cur[t] += u;
        __syncthreads();
    }
    if (t < (1 << BUCKET_SHIFT)) {
        int node = (b << BUCKET_SHIFT) + t;
        int excl = cur[t] - cnt[t];
        if (node < n_nodes) row_start[node] = base0 + excl;
        cur[t] = excl;   // becomes the per-node cursor
    }
    __syncthreads();
    for (int i = t; i < total; i += 256) {
        int e = stage[i];
        int p = atomicAdd(&cur[e >> SRC_BITS], 1);
        sstage[p] = e & SRC_MASK;
    }
    __syncthreads();
    for (int i = t; i < total; i += 256)
        sorted_src[base0 + i] = sstage[i];
}

// ============ Layer 1 gather: wave per node, lane = feature, 8-wide edge unroll ============
__global__ __launch_bounds__(256) void k_gather1(const int* __restrict__ row_start,
                                                 const int* __restrict__ sorted_src,
                                                 const __hip_bfloat16* __restrict__ h1b,
                                                 const float* __restrict__ es1,
                                                 const float* __restrict__ ed1,
                                                 __hip_bfloat16* __restrict__ h1c, int n_nodes) {
    const int n = blockIdx.x * 4 + (threadIdx.x >> 6);
    if (n >= n_nodes) return;
    const int lane = threadIdx.x & 63;
    const int h = lane >> 3;
    const float edh = ed1[n * H1 + h];
    const int beg = row_start[n], end = row_start[n + 1];
    float acc = 0.f, den = 0.f;
    for (int base = beg; base < end; base += 64) {
        const int m = min(64, end - base);
        const int li = lane < m ? lane : (m - 1);
        const int myS = sorted_src[base + li];
        int j = 0;
        for (; j + 8 <= m; j += 8) {
            const int s0 = __shfl(myS, j, 64),     s1 = __shfl(myS, j + 1, 64);
            const int s2 = __shfl(myS, j + 2, 64), s3 = __shfl(myS, j + 3, 64);
            const int s4 = __shfl(myS, j + 4, 64), s5 = __shfl(myS, j + 5, 64);
            const int s6 = __shfl(myS, j + 6, 64), s7 = __shfl(myS, j + 7, 64);
            float e0 = es1[s0 * H1 + h], e1 = es1[s1 * H1 + h];
            float e2 = es1[s2 * H1 + h], e3 = es1[s3 * H1 + h];
            float e4 = es1[s4 * H1 + h], e5 = es1[s5 * H1 + h];
            float e6 = es1[s6 * H1 + h], e7 = es1[s7 * H1 + h];
            const float f0 = __bfloat162float(h1b[(size_t)s0 * F_MID + lane]);
            const float f1 = __bfloat162float(h1b[(size_t)s1 * F_MID + lane]);
            const float f2 = __bfloat162float(h1b[(size_t)s2 * F_MID + lane]);
            const float f3 = __bfloat162float(h1b[(size_t)s3 * F_MID + lane]);
            const float f4 = __bfloat162float(h1b[(size_t)s4 * F_MID + lane]);
            const float f5 = __bfloat162float(h1b[(size_t)s5 * F_MID + lane]);
            const float f6 = __bfloat162float(h1b[(size_t)s6 * F_MID + lane]);
            const float f7 = __bfloat162float(h1b[(size_t)s7 * F_MID + lane]);
            e0 += edh; e1 += edh; e2 += edh; e3 += edh;
            e4 += edh; e5 += edh; e6 += edh; e7 += edh;
            e0 = e0 > 0.f ? e0 : NEG_SLOPE * e0;
            e1 = e1 > 0.f ? e1 : NEG_SLOPE * e1;
            e2 = e2 > 0.f ? e2 : NEG_SLOPE * e2;
            e3 = e3 > 0.f ? e3 : NEG_SLOPE * e3;
            e4 = e4 > 0.f ? e4 : NEG_SLOPE * e4;
            e5 = e5 > 0.f ? e5 : NEG_SLOPE * e5;
            e6 = e6 > 0.f ? e6 : NEG_SLOPE * e6;
            e7 = e7 > 0.f ? e7 : NEG_SLOPE * e7;
            const float w0 = __expf(e0), w1 = __expf(e1), w2 = __expf(e2), w3 = __expf(e3);
            const float w4 = __expf(e4), w5 = __expf(e5), w6 = __expf(e6), w7 = __expf(e7);
            acc += (w0 * f0 + w1 * f1 + w2 * f2 + w3 * f3)
                 + (w4 * f4 + w5 * f5 + w6 * f6 + w7 * f7);
            den += ((w0 + w1) + (w2 + w3)) + ((w4 + w5) + (w6 + w7));
        }
        for (; j + 4 <= m; j += 4) {
            const int s0 = __shfl(myS, j, 64), s1 = __shfl(myS, j + 1, 64);
            const int s2 = __shfl(myS, j + 2, 64), s3 = __shfl(myS, j + 3, 64);
            float e0 = es1[s0 * H1 + h], e1 = es1[s1 * H1 + h];
            float e2 = es1[s2 * H1 + h], e3 = es1[s3 * H1 + h];
            const float f0 = __bfloat162float(h1b[(size_t)s0 * F_MID + lane]);
            const float f1 = __bfloat162float(h1b[(size_t)s1 * F_MID + lane]);
            const float f2 = __bfloat162float(h1b[(size_t)s2 * F_MID + lane]);
            const float f3 = __bfloat162float(h1b[(size_t)s3 * F_MID + lane]);
            e0 += edh; e1 += edh; e2 += edh; e3 += edh;
            e0 = e0 > 0.f ? e0 : NEG_SLOPE * e0;
            e1 = e1 > 0.f ? e1 : NEG_SLOPE * e1;
            e2 = e2 > 0.f ? e2 : NEG_SLOPE * e2;
            e3 = e3 > 0.f ? e3 : NEG_SLOPE * e3;
            const float w0 = __expf(e0), w1 = __expf(e1), w2 = __expf(e2), w3 = __expf(e3);
            acc += w0 * f0 + w1 * f1 + w2 * f2 + w3 * f3;
            den += (w0 + w1) + (w2 + w3);
        }
        for (; j < m; ++j) {
            const int s = __shfl(myS, j, 64);
            float ev = es1[s * H1 + h] + edh;
            ev = ev > 0.f ? ev : NEG_SLOPE * ev;
            const float w = __expf(ev);
            acc += w * __bfloat162float(h1b[(size_t)s * F_MID + lane]);
            den += w;
        }
    }
    float evs = es1[n * H1 + h] + edh;
    evs = evs > 0.f ? evs : NEG_SLOPE * evs;
    const float ws = __expf(evs);
    acc += ws * __bfloat162float(h1b[(size_t)n * F_MID + lane]);
    den += ws;
    float v = acc / den;
    v = v > 0.f ? v : expm1f(v);   // ELU
    h1c[(size_t)n * F_MID + lane] = __float2bfloat16(v);
}

// ============ Layer 2 transform: h1c[N,64] bf16 @ W2[64,16] -> h2b (bf16) + es2/ed2 ============
__global__ void k_gemm2(const __hip_bfloat16* __restrict__ h1c, const float* __restrict__ W2,
                        const float* __restrict__ a2s, const float* __restrict__ a2d,
                        __hip_bfloat16* __restrict__ h2b, float* __restrict__ es2,
                        float* __restrict__ ed2, int n_nodes) {
    __shared__ float w2s[F_MID * C];
    __shared__ float h1s[16][F_MID + 1];
    const int t = threadIdx.x;
    const int nb = blockIdx.x * 16;
    for (int i = t; i < F_MID * C; i += 256) w2s[i] = W2[i];
    {
        int r = t >> 4, k4 = (t & 15) << 2;
        int n = nb + r;
        const __hip_bfloat16* p = h1c + (size_t)(n < n_nodes ? n : n_nodes - 1) * F_MID + k4;
        ushort4 v = *(const ushort4*)p;
        h1s[r][k4 + 0] = __bfloat162float(*(const __hip_bfloat16*)&v.x);
        h1s[r][k4 + 1] = __bfloat162float(*(const __hip_bfloat16*)&v.y);
        h1s[r][k4 + 2] = __bfloat162float(*(const __hip_bfloat16*)&v.z);
        h1s[r][k4 + 3] = __bfloat162float(*(const __hip_bfloat16*)&v.w);
    }
    __syncthreads();
    const int r = t >> 4, c = t & 15;
    const int n = nb + r;
    float acc = 0.f;
#pragma unroll
    for (int k = 0; k < F_MID; ++k) acc += h1s[r][k] * w2s[k * C + c];
    float vs = acc * a2s[c], vd = acc * a2d[c];
#pragma unroll
    for (int off = 1; off < 16; off <<= 1) {
        vs += __shfl_xor(vs, off, 64);
        vd += __shfl_xor(vd, off, 64);
    }
    if (n < n_nodes) {
        h2b[(size_t)n * C + c] = __float2bfloat16(acc);
        if (c == 0) { es2[n] = vs; ed2[n] = vd; }
    }
}

// ============ Layer 2 gather + log_softmax: weights precomputed per-lane (parallel es2 loads) ============
__global__ __launch_bounds__(256) void k_gather2(const int* __restrict__ row_start,
                                                 const int* __restrict__ sorted_src,
                                                 const __hip_bfloat16* __restrict__ h2b,
                                                 const float* __restrict__ es2,
                                                 const float* __restrict__ ed2,
                                                 float* __restrict__ out, int n_nodes) {
    const int n = blockIdx.x * 16 + (threadIdx.x >> 4);
    if (n >= n_nodes) return;
    const int lane = threadIdx.x & 63;
    const int c = lane & 15;
    const int g = lane >> 4;
    const float ed = ed2[n];
    const int beg = row_start[n], end = row_start[n + 1];
    float acc = 0.f, den = 0.f;
    for (int base = beg; base < end; base += 16) {
        const int m = min(16, end - base);
        const int li = c < m ? c : (m - 1);
        const int myS = sorted_src[base + li];
        float evp = es2[myS] + ed;
        evp = evp > 0.f ? evp : NEG_SLOPE * evp;
        const float wli = __expf(evp);
        int j = 0;
        for (; j + 4 <= m; j += 4) {
            const int s0 = __shfl(myS, g * 16 + j, 64), s1 = __shfl(myS, g * 16 + j + 1, 64);
            const int s2 = __shfl(myS, g * 16 + j + 2, 64), s3 = __shfl(myS, g * 16 + j + 3, 64);
            const float w0 = __shfl(wli, g * 16 + j, 64), w1 = __shfl(wli, g * 16 + j + 1, 64);
            const float w2 = __shfl(wli, g * 16 + j + 2, 64), w3 = __shfl(wli, g * 16 + j + 3, 64);
            const float f0 = __bfloat162float(h2b[(size_t)s0 * C + c]);
            const float f1 = __bfloat162float(h2b[(size_t)s1 * C + c]);
            const float f2 = __bfloat162float(h2b[(size_t)s2 * C + c]);
            const float f3 = __bfloat162float(h2b[(size_t)s3 * C + c]);
            acc += w0 * f0 + w1 * f1 + w2 * f2 + w3 * f3;
            den += (w0 + w1) + (w2 + w3);
        }
        for (; j < m; ++j) {
            const int s = __shfl(myS, g * 16 + j, 64);
            const float w = __shfl(wli, g * 16 + j, 64);
            acc += w * __bfloat162float(h2b[(size_t)s * C + c]);
            den += w;
        }
    }
    float evs = es2[n] + ed;
    evs = evs > 0.f ? evs : NEG_SLOPE * evs;
    const float ws = __expf(evs);
    acc += ws * __bfloat162float(h2b[(size_t)n * C + c]);
    den += ws;
    const float v = acc / den;
    float mx = v;
#pragma unroll
    for (int off = 1; off < 16; off <<= 1) mx = fmaxf(mx, __shfl_xor(mx, off, 64));
    float se = __expf(v - mx);
#pragma unroll
    for (int off = 1; off < 16; off <<= 1) se += __shfl_xor(se, off, 64);
    out[(size_t)n * C + c] = v - mx - __logf(se);
}

extern "C" void kernel_launch(void* const* d_in, const int* in_sizes, int n_in,
                              void* d_out, int out_size, void* d_ws, size_t ws_size,
                              hipStream_t stream) {
    const float* x   = (const float*)d_in[0];
    const int*   ei  = (const int*)d_in[1];
    const float* W1  = (const float*)d_in[2];
    const float* a1s = (const float*)d_in[3];
    const float* a1d = (const float*)d_in[4];
    const float* W2  = (const float*)d_in[5];
    const float* a2s = (const float*)d_in[6];
    const float* a2d = (const float*)d_in[7];
    float* out = (float*)d_out;

    const int n_nodes = in_sizes[0] / F_IN;   // 100000
    const int n_edges = in_sizes[1] / 2;      // 1600000
    const int* src = ei;
    const int* dst = ei + n_edges;
    const int nb = (n_nodes + (1 << BUCKET_SHIFT) - 1) >> BUCKET_SHIFT;   // 782
    const int nbin = (n_edges + BIN_CHUNK - 1) / BIN_CHUNK;               // 391
    const int ngemm = (n_nodes + 63) / 64;                                // 1563

    // workspace layout
    float* fws = (float*)d_ws;
    float* es1 = fws;                              // N*8
    float* ed1 = es1 + (size_t)n_nodes * H1;       // N*8
    float* es2 = ed1 + (size_t)n_nodes * H1;       // N
    float* ed2 = es2 + n_nodes;                    // N
    __hip_bfloat16* h1b = (__hip_bfloat16*)(ed2 + n_nodes);   // N*64 bf16
    __hip_bfloat16* h2b = h1b + (size_t)n_nodes * F_MID;      // N*16 bf16
    __hip_bfloat16* h1c = h2b + (size_t)n_nodes * C;          // N*64 bf16 (post-ELU)
    __hip_bfloat16* w1t = h1c + (size_t)n_nodes * F_MID;      // 64*512 bf16
    int* iws         = (int*)(w1t + F_IN * F_MID);
    int* gcur        = iws;                        // NB_MAX (zeroed by k_init)
    int* row_start   = gcur + NB_MAX;              // N+1
    int* sorted_src  = row_start + n_nodes + 1;    // E
    int* bucketed    = sorted_src + n_edges;       // NB_MAX*3072 int (packed)

    // prologue: w1t transpose + gcur zero
    k_init<<<(F_IN * F_MID) / 256 + 1, 256, 0, stream>>>(W1, w1t, gcur);

    // CSR bin (block-local counting sort, coalesced bucketed writes)
    k_bin<<<nbin, 256, 0, stream>>>(src, dst, gcur, bucketed, n_edges);

    // Layer-1 GEMM + CSR place (fused heterogeneous grid; mutually independent)
    k_gemm1_place<<<ngemm + nb, 256, 0, stream>>>(x, w1t, a1s, a1d, h1b, es1, ed1,
                                                  gcur, bucketed, row_start, sorted_src,
                                                  n_nodes, n_edges, ngemm);

    // Layer 1 gather
    k_gather1<<<(n_nodes + 3) / 4, 256, 0, stream>>>(row_start, sorted_src, h1b, es1, ed1, h1c, n_nodes);

    // Layer 2
    k_gemm2<<<(n_nodes + 15) / 16, 256, 0, stream>>>(h1c, W2, a2s, a2d, h2b, es2, ed2, n_nodes);
    k_gather2<<<(n_nodes + 15) / 16, 256, 0, stream>>>(row_start, sorted_src, h2b, es2, ed2, out, n_nodes);
}

// Round 12
// 467.816 us; speedup vs baseline: 1.0475x; 1.0223x over previous
//
#include <hip/hip_runtime.h>
#include <hip/hip_bf16.h>

#define F_IN 512
#define H1 8
#define D1 8
#define F_MID 64   // H1*D1
#define C 16
#define NEG_SLOPE 0.2f
#define BIN_CHUNK 4096
#define NB_MAX 1024
#define BUCKET_SHIFT 7        // 128 nodes per bucket
#define BUCKET_STRIDE 3072    // capacity per bucket (mean 2048, +22 sigma)
#define SRC_BITS 17           // n_nodes = 100000 < 2^17
#define SRC_MASK ((1 << SRC_BITS) - 1)

typedef __attribute__((ext_vector_type(8))) short bf16x8;
typedef __attribute__((ext_vector_type(4))) float f32x4;

static __device__ __forceinline__ unsigned short f2bf(float f) {
    __hip_bfloat16 h = __float2bfloat16(f);
    return *(unsigned short*)&h;
}

// ============ fused: bucket-bin pass (blocks < nbin) + W1 transpose (blocks >= nbin) ============
__global__ __launch_bounds__(256) void k_bin_w1t(const int* __restrict__ src,
                                                 const int* __restrict__ dst,
                                                 int* __restrict__ gcur,
                                                 int* __restrict__ bucketed,
                                                 const float* __restrict__ W1,
                                                 __hip_bfloat16* __restrict__ w1t,
                                                 int n_edges, int nb, int nbin) {
    const int t = threadIdx.x;
    if ((int)blockIdx.x >= nbin) {
        // W1[512,64] -> W1T[64,512] bf16
        int idx = ((int)blockIdx.x - nbin) * 256 + t;
        int k = idx >> 6, n = idx & 63;
        w1t[n * F_IN + k] = __float2bfloat16(W1[idx]);
        return;
    }
    __shared__ int cnt[NB_MAX];
    __shared__ int base[NB_MAX];
    const int eb = blockIdx.x * BIN_CHUNK;
    // cache dst chunk in registers (read once)
    int dc[BIN_CHUNK / 256];
#pragma unroll
    for (int i = 0; i < BIN_CHUNK / 256; ++i) {
        int e = eb + i * 256 + t;
        dc[i] = (e < n_edges) ? dst[e] : -1;
    }
    for (int b = t; b < nb; b += 256) cnt[b] = 0;
    __syncthreads();
#pragma unroll
    for (int i = 0; i < BIN_CHUNK / 256; ++i)
        if (dc[i] >= 0) atomicAdd(&cnt[dc[i] >> BUCKET_SHIFT], 1);
    __syncthreads();
    for (int b = t; b < nb; b += 256) {
        int c = cnt[b];
        base[b] = c > 0 ? atomicAdd(&gcur[b], c) : 0;
        cnt[b] = 0;
    }
    __syncthreads();
#pragma unroll
    for (int i = 0; i < BIN_CHUNK / 256; ++i) {
        if (dc[i] >= 0) {
            int e = eb + i * 256 + t;
            int d = dc[i];
            int b = d >> BUCKET_SHIFT;
            int local = atomicAdd(&cnt[b], 1);
            bucketed[(size_t)b * BUCKET_STRIDE + base[b] + local] =
                ((d & ((1 << BUCKET_SHIFT) - 1)) << SRC_BITS) | src[e];
        }
    }
}

// ============ fused heterogeneous launch: gemm1 (blocks < ngemm) + place (blocks >= ngemm) ====
// The two halves are mutually independent (gemm1: {x,w1t} -> h1b/es1/ed1;
// place: {gcur,bucketed} -> row_start/sorted_src). gemm1 is HBM-streaming-bound,
// place is LDS/latency-bound -> co-scheduling fills complementary resources and
// removes one full launch-drain boundary.
__global__ __launch_bounds__(256) void k_gemm1_place(const float* __restrict__ x,
                                                     const __hip_bfloat16* __restrict__ w1t,
                                                     const float* __restrict__ a1s,
                                                     const float* __restrict__ a1d,
                                                     __hip_bfloat16* __restrict__ h1b,
                                                     float* __restrict__ es1,
                                                     float* __restrict__ ed1,
                                                     const int* __restrict__ gcur,
                                                     const int* __restrict__ bucketed,
                                                     int* __restrict__ row_start,
                                                     int* __restrict__ sorted_src,
                                                     int n_nodes, int n_edges, int ngemm) {
    __shared__ int stage[BUCKET_STRIDE];
    __shared__ int cnt[1 << BUCKET_SHIFT];
    __shared__ int cur[1 << BUCKET_SHIFT];
    __shared__ int wsum[4];
    const int t = threadIdx.x;

    if ((int)blockIdx.x < ngemm) {
        // ---------------- gemm1 path (zero-LDS-usage, zero barriers) ----------------
        const int wv = t >> 6, l = t & 63;
        const int q = l >> 4, m16 = l & 15;
        const int rowbase = blockIdx.x * 64;

        const int node = rowbase + wv * 16 + m16;
        const int gx = node < n_nodes ? node : n_nodes - 1;
        const float* xrow = x + (size_t)gx * F_IN;

        f32x4 acc[4];
#pragma unroll
        for (int i = 0; i < 4; ++i) acc[i] = (f32x4){0.f, 0.f, 0.f, 0.f};

        for (int kt = 0; kt < F_IN; kt += 64) {
#pragma unroll
            for (int kk = 0; kk < 2; ++kk) {
                const float* xp = xrow + kt + kk * 32 + q * 8;
                float4 v0 = *(const float4*)(xp);
                float4 v1 = *(const float4*)(xp + 4);
                ushort4 b0, b1;
                b0.x = f2bf(v0.x); b0.y = f2bf(v0.y); b0.z = f2bf(v0.z); b0.w = f2bf(v0.w);
                b1.x = f2bf(v1.x); b1.y = f2bf(v1.y); b1.z = f2bf(v1.z); b1.w = f2bf(v1.w);
                union { ushort4 u4[2]; bf16x8 v8; } bu;
                bu.u4[0] = b0; bu.u4[1] = b1;
                const bf16x8 bfrag = bu.v8;
#pragma unroll
                for (int tn = 0; tn < 4; ++tn) {
                    bf16x8 afrag = *(const bf16x8*)(w1t + (size_t)(tn * 16 + m16) * F_IN
                                                    + kt + kk * 32 + q * 8);
                    acc[tn] = __builtin_amdgcn_mfma_f32_16x16x32_bf16(afrag, bfrag, acc[tn], 0, 0, 0);
                }
            }
        }

        const bool ok = node < n_nodes;
#pragma unroll
        for (int tn = 0; tn < 4; ++tn) {
            const f32x4 a = acc[tn];
            const int nw0 = tn * 16 + q * 4;
            float vs = a.x * a1s[nw0] + a.y * a1s[nw0 + 1] + a.z * a1s[nw0 + 2] + a.w * a1s[nw0 + 3];
            float vd = a.x * a1d[nw0] + a.y * a1d[nw0 + 1] + a.z * a1d[nw0 + 2] + a.w * a1d[nw0 + 3];
            vs += __shfl_xor(vs, 16, 64);
            vd += __shfl_xor(vd, 16, 64);
            if (ok) {
                ushort4 b;
                b.x = f2bf(a.x); b.y = f2bf(a.y); b.z = f2bf(a.z); b.w = f2bf(a.w);
                *(ushort4*)(h1b + (size_t)node * F_MID + nw0) = b;
                if ((q & 1) == 0) {
                    const int head = 2 * tn + (q >> 1);
                    es1[node * H1 + head] = vs;
                    ed1[node * H1 + head] = vd;
                }
            }
        }
        return;
    }

    // ---------------- place path ----------------
    const int b = (int)blockIdx.x - ngemm;
    if (t < (1 << BUCKET_SHIFT)) cnt[t] = 0;
    // exclusive prefix over bucket totals: base0 = sum(gcur[0..b-1]) (L2-resident)
    int pre = 0;
    for (int j = t; j < b; j += 256) pre += gcur[j];
#pragma unroll
    for (int off = 1; off < 64; off <<= 1) pre += __shfl_xor(pre, off, 64);
    if ((t & 63) == 0) wsum[t >> 6] = pre;
    __syncthreads();
    const int base0 = wsum[0] + wsum[1] + wsum[2] + wsum[3];
    if (b == 0 && t == 0) row_start[n_nodes] = n_edges;

    const int total = gcur[b];
    const int* bp = bucketed + (size_t)b * BUCKET_STRIDE;
    for (int i = t; i < total; i += 256) {
        int e = bp[i];
        stage[i] = e;
        atomicAdd(&cnt[e >> SRC_BITS], 1);
    }
    __syncthreads();
    // inclusive Hillis-Steele over 128 counts
    if (t < (1 << BUCKET_SHIFT)) cur[t] = cnt[t];
    __syncthreads();
#pragma unroll
    for (int d = 1; d < (1 << BUCKET_SHIFT); d <<= 1) {
        int u = 0;
        if (t < (1 << BUCKET_SHIFT) && t >= d) u = cur[t - d];
        __syncthreads();
        if (t < (1 << BUCKET_SHIFT)) cur[t] += u;
        __syncthreads();
    }
    if (t < (1 << BUCKET_SHIFT)) {
        int node = (b << BUCKET_SHIFT) + t;
        int excl = cur[t] - cnt[t];
        if (node < n_nodes) row_start[node] = base0 + excl;
        cur[t] = excl;   // becomes the per-node cursor
    }
    __syncthreads();
    for (int i = t; i < total; i += 256) {
        int e = stage[i];
        int p = atomicAdd(&cur[e >> SRC_BITS], 1);
        sorted_src[base0 + p] = e & SRC_MASK;
    }
}

// ============ Layer 1 gather: wave per node, lane = feature, 8-wide edge unroll ============
__global__ __launch_bounds__(256) void k_gather1(const int* __restrict__ row_start,
                                                 const int* __restrict__ sorted_src,
                                                 const __hip_bfloat16* __restrict__ h1b,
                                                 const float* __restrict__ es1,
                                                 const float* __restrict__ ed1,
                                                 __hip_bfloat16* __restrict__ h1c, int n_nodes) {
    const int n = blockIdx.x * 4 + (threadIdx.x >> 6);
    if (n >= n_nodes) return;
    const int lane = threadIdx.x & 63;
    const int h = lane >> 3;
    const float edh = ed1[n * H1 + h];
    const int beg = row_start[n], end = row_start[n + 1];
    float acc = 0.f, den = 0.f;
    for (int base = beg; base < end; base += 64) {
        const int m = min(64, end - base);
        const int li = lane < m ? lane : (m - 1);
        const int myS = sorted_src[base + li];
        int j = 0;
        for (; j + 8 <= m; j += 8) {
            const int s0 = __shfl(myS, j, 64),     s1 = __shfl(myS, j + 1, 64);
            const int s2 = __shfl(myS, j + 2, 64), s3 = __shfl(myS, j + 3, 64);
            const int s4 = __shfl(myS, j + 4, 64), s5 = __shfl(myS, j + 5, 64);
            const int s6 = __shfl(myS, j + 6, 64), s7 = __shfl(myS, j + 7, 64);
            float e0 = es1[s0 * H1 + h], e1 = es1[s1 * H1 + h];
            float e2 = es1[s2 * H1 + h], e3 = es1[s3 * H1 + h];
            float e4 = es1[s4 * H1 + h], e5 = es1[s5 * H1 + h];
            float e6 = es1[s6 * H1 + h], e7 = es1[s7 * H1 + h];
            const float f0 = __bfloat162float(h1b[(size_t)s0 * F_MID + lane]);
            const float f1 = __bfloat162float(h1b[(size_t)s1 * F_MID + lane]);
            const float f2 = __bfloat162float(h1b[(size_t)s2 * F_MID + lane]);
            const float f3 = __bfloat162float(h1b[(size_t)s3 * F_MID + lane]);
            const float f4 = __bfloat162float(h1b[(size_t)s4 * F_MID + lane]);
            const float f5 = __bfloat162float(h1b[(size_t)s5 * F_MID + lane]);
            const float f6 = __bfloat162float(h1b[(size_t)s6 * F_MID + lane]);
            const float f7 = __bfloat162float(h1b[(size_t)s7 * F_MID + lane]);
            e0 += edh; e1 += edh; e2 += edh; e3 += edh;
            e4 += edh; e5 += edh; e6 += edh; e7 += edh;
            e0 = e0 > 0.f ? e0 : NEG_SLOPE * e0;
            e1 = e1 > 0.f ? e1 : NEG_SLOPE * e1;
            e2 = e2 > 0.f ? e2 : NEG_SLOPE * e2;
            e3 = e3 > 0.f ? e3 : NEG_SLOPE * e3;
            e4 = e4 > 0.f ? e4 : NEG_SLOPE * e4;
            e5 = e5 > 0.f ? e5 : NEG_SLOPE * e5;
            e6 = e6 > 0.f ? e6 : NEG_SLOPE * e6;
            e7 = e7 > 0.f ? e7 : NEG_SLOPE * e7;
            const float w0 = __expf(e0), w1 = __expf(e1), w2 = __expf(e2), w3 = __expf(e3);
            const float w4 = __expf(e4), w5 = __expf(e5), w6 = __expf(e6), w7 = __expf(e7);
            acc += (w0 * f0 + w1 * f1 + w2 * f2 + w3 * f3)
                 + (w4 * f4 + w5 * f5 + w6 * f6 + w7 * f7);
            den += ((w0 + w1) + (w2 + w3)) + ((w4 + w5) + (w6 + w7));
        }
        for (; j + 4 <= m; j += 4) {
            const int s0 = __shfl(myS, j, 64), s1 = __shfl(myS, j + 1, 64);
            const int s2 = __shfl(myS, j + 2, 64), s3 = __shfl(myS, j + 3, 64);
            float e0 = es1[s0 * H1 + h], e1 = es1[s1 * H1 + h];
            float e2 = es1[s2 * H1 + h], e3 = es1[s3 * H1 + h];
            const float f0 = __bfloat162float(h1b[(size_t)s0 * F_MID + lane]);
            const float f1 = __bfloat162float(h1b[(size_t)s1 * F_MID + lane]);
            const float f2 = __bfloat162float(h1b[(size_t)s2 * F_MID + lane]);
            const float f3 = __bfloat162float(h1b[(size_t)s3 * F_MID + lane]);
            e0 += edh; e1 += edh; e2 += edh; e3 += edh;
            e0 = e0 > 0.f ? e0 : NEG_SLOPE * e0;
            e1 = e1 > 0.f ? e1 : NEG_SLOPE * e1;
            e2 = e2 > 0.f ? e2 : NEG_SLOPE * e2;
            e3 = e3 > 0.f ? e3 : NEG_SLOPE * e3;
            const float w0 = __expf(e0), w1 = __expf(e1), w2 = __expf(e2), w3 = __expf(e3);
            acc += w0 * f0 + w1 * f1 + w2 * f2 + w3 * f3;
            den += (w0 + w1) + (w2 + w3);
        }
        for (; j < m; ++j) {
            const int s = __shfl(myS, j, 64);
            float ev = es1[s * H1 + h] + edh;
            ev = ev > 0.f ? ev : NEG_SLOPE * ev;
            const float w = __expf(ev);
            acc += w * __bfloat162float(h1b[(size_t)s * F_MID + lane]);
            den += w;
        }
    }
    float evs = es1[n * H1 + h] + edh;
    evs = evs > 0.f ? evs : NEG_SLOPE * evs;
    const float ws = __expf(evs);
    acc += ws * __bfloat162float(h1b[(size_t)n * F_MID + lane]);
    den += ws;
    float v = acc / den;
    v = v > 0.f ? v : expm1f(v);   // ELU
    h1c[(size_t)n * F_MID + lane] = __float2bfloat16(v);
}

// ============ Layer 2 transform: h1c[N,64] bf16 @ W2[64,16] -> h2b (bf16) + es2/ed2 ============
__global__ void k_gemm2(const __hip_bfloat16* __restrict__ h1c, const float* __restrict__ W2,
                        const float* __restrict__ a2s, const float* __restrict__ a2d,
                        __hip_bfloat16* __restrict__ h2b, float* __restrict__ es2,
                        float* __restrict__ ed2, int n_nodes) {
    __shared__ float w2s[F_MID * C];
    __shared__ float h1s[16][F_MID + 1];
    const int t = threadIdx.x;
    const int nb = blockIdx.x * 16;
    for (int i = t; i < F_MID * C; i += 256) w2s[i] = W2[i];
    {
        // 16 rows x 16 ushort4-groups = 256 units, one per thread
        int r = t >> 4, k4 = (t & 15) << 2;
        int n = nb + r;
        const __hip_bfloat16* p = h1c + (size_t)(n < n_nodes ? n : n_nodes - 1) * F_MID + k4;
        ushort4 v = *(const ushort4*)p;
        h1s[r][k4 + 0] = __bfloat162float(*(const __hip_bfloat16*)&v.x);
        h1s[r][k4 + 1] = __bfloat162float(*(const __hip_bfloat16*)&v.y);
        h1s[r][k4 + 2] = __bfloat162float(*(const __hip_bfloat16*)&v.z);
        h1s[r][k4 + 3] = __bfloat162float(*(const __hip_bfloat16*)&v.w);
    }
    __syncthreads();
    const int r = t >> 4, c = t & 15;
    const int n = nb + r;
    float acc = 0.f;
#pragma unroll
    for (int k = 0; k < F_MID; ++k) acc += h1s[r][k] * w2s[k * C + c];
    float vs = acc * a2s[c], vd = acc * a2d[c];
#pragma unroll
    for (int off = 1; off < 16; off <<= 1) {
        vs += __shfl_xor(vs, off, 64);
        vd += __shfl_xor(vd, off, 64);
    }
    if (n < n_nodes) {
        h2b[(size_t)n * C + c] = __float2bfloat16(acc);
        if (c == 0) { es2[n] = vs; ed2[n] = vd; }
    }
}

// ============ Layer 2 gather + log_softmax: weights precomputed per-lane (parallel es2 loads) ============
__global__ __launch_bounds__(256) void k_gather2(const int* __restrict__ row_start,
                                                 const int* __restrict__ sorted_src,
                                                 const __hip_bfloat16* __restrict__ h2b,
                                                 const float* __restrict__ es2,
                                                 const float* __restrict__ ed2,
                                                 float* __restrict__ out, int n_nodes) {
    const int n = blockIdx.x * 16 + (threadIdx.x >> 4);
    if (n >= n_nodes) return;
    const int lane = threadIdx.x & 63;
    const int c = lane & 15;
    const int g = lane >> 4;
    const float ed = ed2[n];
    const int beg = row_start[n], end = row_start[n + 1];
    float acc = 0.f, den = 0.f;
    for (int base = beg; base < end; base += 16) {
        const int m = min(16, end - base);
        const int li = c < m ? c : (m - 1);
        const int myS = sorted_src[base + li];
        // parallel weight precompute: one es2 load per lane, all in flight at once
        float evp = es2[myS] + ed;
        evp = evp > 0.f ? evp : NEG_SLOPE * evp;
        const float wli = __expf(evp);
        int j = 0;
        for (; j + 4 <= m; j += 4) {
            const int s0 = __shfl(myS, g * 16 + j, 64), s1 = __shfl(myS, g * 16 + j + 1, 64);
            const int s2 = __shfl(myS, g * 16 + j + 2, 64), s3 = __shfl(myS, g * 16 + j + 3, 64);
            const float w0 = __shfl(wli, g * 16 + j, 64), w1 = __shfl(wli, g * 16 + j + 1, 64);
            const float w2 = __shfl(wli, g * 16 + j + 2, 64), w3 = __shfl(wli, g * 16 + j + 3, 64);
            const float f0 = __bfloat162float(h2b[(size_t)s0 * C + c]);
            const float f1 = __bfloat162float(h2b[(size_t)s1 * C + c]);
            const float f2 = __bfloat162float(h2b[(size_t)s2 * C + c]);
            const float f3 = __bfloat162float(h2b[(size_t)s3 * C + c]);
            acc += w0 * f0 + w1 * f1 + w2 * f2 + w3 * f3;
            den += (w0 + w1) + (w2 + w3);
        }
        for (; j < m; ++j) {
            const int s = __shfl(myS, g * 16 + j, 64);
            const float w = __shfl(wli, g * 16 + j, 64);
            acc += w * __bfloat162float(h2b[(size_t)s * C + c]);
            den += w;
        }
    }
    float evs = es2[n] + ed;
    evs = evs > 0.f ? evs : NEG_SLOPE * evs;
    const float ws = __expf(evs);
    acc += ws * __bfloat162float(h2b[(size_t)n * C + c]);
    den += ws;
    const float v = acc / den;
    float mx = v;
#pragma unroll
    for (int off = 1; off < 16; off <<= 1) mx = fmaxf(mx, __shfl_xor(mx, off, 64));
    float se = __expf(v - mx);
#pragma unroll
    for (int off = 1; off < 16; off <<= 1) se += __shfl_xor(se, off, 64);
    out[(size_t)n * C + c] = v - mx - __logf(se);
}

extern "C" void kernel_launch(void* const* d_in, const int* in_sizes, int n_in,
                              void* d_out, int out_size, void* d_ws, size_t ws_size,
                              hipStream_t stream) {
    const float* x   = (const float*)d_in[0];
    const int*   ei  = (const int*)d_in[1];
    const float* W1  = (const float*)d_in[2];
    const float* a1s = (const float*)d_in[3];
    const float* a1d = (const float*)d_in[4];
    const float* W2  = (const float*)d_in[5];
    const float* a2s = (const float*)d_in[6];
    const float* a2d = (const float*)d_in[7];
    float* out = (float*)d_out;

    const int n_nodes = in_sizes[0] / F_IN;   // 100000
    const int n_edges = in_sizes[1] / 2;      // 1600000
    const int* src = ei;
    const int* dst = ei + n_edges;
    const int nb = (n_nodes + (1 << BUCKET_SHIFT) - 1) >> BUCKET_SHIFT;   // 782
    const int nbin = (n_edges + BIN_CHUNK - 1) / BIN_CHUNK;               // 391
    const int ngemm = (n_nodes + 63) / 64;                                // 1563

    // workspace layout
    float* fws = (float*)d_ws;
    float* es1 = fws;                              // N*8
    float* ed1 = es1 + (size_t)n_nodes * H1;       // N*8
    float* es2 = ed1 + (size_t)n_nodes * H1;       // N
    float* ed2 = es2 + n_nodes;                    // N
    __hip_bfloat16* h1b = (__hip_bfloat16*)(ed2 + n_nodes);   // N*64 bf16
    __hip_bfloat16* h2b = h1b + (size_t)n_nodes * F_MID;      // N*16 bf16
    __hip_bfloat16* h1c = h2b + (size_t)n_nodes * C;          // N*64 bf16 (post-ELU)
    __hip_bfloat16* w1t = h1c + (size_t)n_nodes * F_MID;      // 64*512 bf16
    int* iws         = (int*)(w1t + F_IN * F_MID);
    int* gcur        = iws;                        // NB_MAX (zeroed)
    int* row_start   = gcur + NB_MAX;              // N+1
    int* sorted_src  = row_start + n_nodes + 1;    // E
    int* bucketed    = sorted_src + n_edges;       // NB_MAX*3072 int (packed)

    hipMemsetAsync(gcur, 0, NB_MAX * sizeof(int), stream);

    // CSR bin + W1 transpose (fused grid)
    k_bin_w1t<<<nbin + (F_IN * F_MID) / 256, 256, 0, stream>>>(src, dst, gcur, bucketed,
                                                               W1, w1t, n_edges, nb, nbin);

    // Layer-1 GEMM + CSR place (fused heterogeneous grid; mutually independent)
    k_gemm1_place<<<ngemm + nb, 256, 0, stream>>>(x, w1t, a1s, a1d, h1b, es1, ed1,
                                                  gcur, bucketed, row_start, sorted_src,
                                                  n_nodes, n_edges, ngemm);

    // Layer 1 gather
    k_gather1<<<(n_nodes + 3) / 4, 256, 0, stream>>>(row_start, sorted_src, h1b, es1, ed1, h1c, n_nodes);

    // Layer 2
    k_gemm2<<<(n_nodes + 15) / 16, 256, 0, stream>>>(h1c, W2, a2s, a2d, h2b, es2, ed2, n_nodes);
    k_gather2<<<(n_nodes + 15) / 16, 256, 0, stream>>>(row_start, sorted_src, h2b, es2, ed2, out, n_nodes);
}